// Round 3
// baseline (2460.657 us; speedup 1.0000x reference)
//
#include <hip/hip_runtime.h>
#include <math.h>

#define NBATCH 1024
#define LATD 64
#define HIDD 128
#define NOISED 16
#define OUTD 32
#define INOISED 64
#define TT 128
#define NB 4   // batch rows per block

// ws layout, offsets in 4-byte units
#define DW1R0 0        // f32[128]   drift L1 t-row
#define GW1R0 128      // f32[128]
#define DW1P  256      // u32[32][128]  z-row pairs x outs
#define GW1P  4352     // u32[32][128]
#define DW2P  8448     // u32[64][128]  K-pairs x outs
#define GW2P  16640    // u32[64][128]
#define DW3P  24832    // u32[64][64]   K-pairs x outs
#define GW3P  28928    // u32[64][1024] K-pairs x outs
#define EMBT  94464    // f32[64][64]   (i x o)
#define RO1P  98560    // u32[32][128]
#define RO2P  102656   // u32[64][32]

__device__ __forceinline__ float lipswish(float x) {
  return 0.909f * x / (1.0f + expf(-x));
}
__device__ __forceinline__ uint32_t bf16r(float x) {
  uint32_t u = __float_as_uint(x);
  return ((u + 0x7fffu + ((u >> 16) & 1u)) >> 16) & 0xffffu;
}
__device__ __forceinline__ uint32_t pack2f(float a, float b) {
  return bf16r(a) | (bf16r(b) << 16);
}
__device__ __forceinline__ float bflo(uint32_t w) { return __uint_as_float(w << 16); }
__device__ __forceinline__ float bfhi(uint32_t w) { return __uint_as_float(w & 0xffff0000u); }

// ---------------- prep: weight-norm + transpose + bf16-pack into ws ----------------
__global__ void prep_kernel(const float* dr_v1, const float* dr_g1,
                            const float* dr_v2, const float* dr_g2,
                            const float* dr_v3, const float* dr_g3,
                            const float* di_v1, const float* di_g1,
                            const float* di_v2, const float* di_g2,
                            const float* di_v3, const float* di_g3,
                            const float* emb_W, const float* ro_W1, const float* ro_W2,
                            float* ws) {
  __shared__ float s_row[128];
  __shared__ float sred[2];
  uint32_t* wsu = (uint32_t*)ws;
  float* wsf = ws;
  const int mat = blockIdx.y;
  const int row = blockIdx.x;
  const int i = threadIdx.x;
  const float* v = nullptr; const float* g = nullptr;
  int rows = 0, len = 0;
  switch (mat) {
    case 0: v = dr_v1; g = dr_g1; rows = 128;  len = 65;  break;
    case 1: v = dr_v2; g = dr_g2; rows = 128;  len = 128; break;
    case 2: v = dr_v3; g = dr_g3; rows = 64;   len = 128; break;
    case 3: v = di_v1; g = di_g1; rows = 128;  len = 65;  break;
    case 4: v = di_v2; g = di_g2; rows = 128;  len = 128; break;
    case 5: v = di_v3; g = di_g3; rows = 1024; len = 128; break;
    case 6: v = emb_W; g = nullptr; rows = 64;  len = 64;  break;
    case 7: v = ro_W1; g = nullptr; rows = 128; len = 64;  break;
    case 8: v = ro_W2; g = nullptr; rows = 32;  len = 128; break;
  }
  if (row >= rows) return;
  const float x = (i < len) ? v[(size_t)row * len + i] : 0.0f;
  float scale = 1.0f;
  if (g != nullptr) {
    float ss = x * x;
    #pragma unroll
    for (int d = 1; d < 64; d <<= 1) ss += __shfl_xor(ss, d);
    if ((i & 63) == 0) sred[i >> 6] = ss;
    __syncthreads();
    scale = g[row] / sqrtf(sred[0] + sred[1]);
  }
  s_row[i] = x * scale;
  __syncthreads();
  switch (mat) {
    case 0:
      if (i == 0) wsf[DW1R0 + row] = s_row[0];
      if (i < 32) wsu[DW1P + i * 128 + row] = pack2f(s_row[1 + 2*i], s_row[2 + 2*i]);
      break;
    case 3:
      if (i == 0) wsf[GW1R0 + row] = s_row[0];
      if (i < 32) wsu[GW1P + i * 128 + row] = pack2f(s_row[1 + 2*i], s_row[2 + 2*i]);
      break;
    case 1: if (i < 64) wsu[DW2P + i * 128 + row] = pack2f(s_row[2*i], s_row[2*i + 1]); break;
    case 4: if (i < 64) wsu[GW2P + i * 128 + row] = pack2f(s_row[2*i], s_row[2*i + 1]); break;
    case 2: if (i < 64) wsu[DW3P + i * 64 + row]  = pack2f(s_row[2*i], s_row[2*i + 1]); break;
    case 5: if (i < 64) wsu[GW3P + i * 1024 + row] = pack2f(s_row[2*i], s_row[2*i + 1]); break;
    case 6: if (i < 64) wsf[EMBT + i * 64 + row] = s_row[i]; break;
    case 7: if (i < 32) wsu[RO1P + i * 128 + row] = pack2f(s_row[2*i], s_row[2*i + 1]); break;
    case 8: if (i < 64) wsu[RO2P + i * 32 + row]  = pack2f(s_row[2*i], s_row[2*i + 1]); break;
  }
}

// ---------------- main persistent kernel: 1024 threads, 4 rows/block ----------------
__global__ void __launch_bounds__(1024, 4)
sde_main(const float* __restrict__ init_noise, const float* __restrict__ bm,
         const float* __restrict__ ts_g, const int* __restrict__ p_steps,
         const int* __restrict__ p_mult, const float* __restrict__ emb_b,
         const float* __restrict__ dr_b1, const float* __restrict__ dr_b2, const float* __restrict__ dr_b3,
         const float* __restrict__ di_b1, const float* __restrict__ di_b2, const float* __restrict__ di_b3,
         const float* __restrict__ ro_b1, const float* __restrict__ ro_b2,
         const float* __restrict__ ws, float* __restrict__ out)
{
  __shared__ __align__(16) float s_ts[TT];
  __shared__ __align__(16) float s_y[NB][LATD], s_z[NB][LATD], s_f[NB][LATD], s_v[NB][LATD];
  __shared__ __align__(16) float s_dwi[NB][NOISED], s_dwn[NB][NOISED];
  __shared__ __align__(16) float s_h1[2][NB][HIDD], s_h2[2][NB][HIDD];
  __shared__ __align__(16) float s_p[32 * 128];        // partials / readout h
  __shared__ __align__(16) float s_pd[8][NB][LATD];
  __shared__ __align__(16) float s_u[NB][LATD], s_vn[NB][LATD];
  __shared__ __align__(16) float s_ybuf[8][NB][LATD];
  __shared__ __align__(16) float s_b1[2][HIDD], s_b2[2][HIDD], s_b3d[LATD], s_b3g[1024];
  __shared__ __align__(16) float s_rob1[HIDD], s_rob2[OUTD];

  const int t = threadIdx.x;
  const int b0 = blockIdx.x * NB;
  const int steps = p_steps[0];
  const int mult  = p_mult[0];
  const uint32_t* __restrict__ wsu = (const uint32_t*)ws;
  const float* __restrict__ wsf = ws;

  // ---- stage constants ----
  if (t < TT) s_ts[t] = ts_g[t];
  if (t >= 128 && t < 256) { const int i = t - 128; s_b1[0][i] = dr_b1[i]; s_b1[1][i] = di_b1[i]; }
  if (t >= 256 && t < 384) { const int i = t - 256; s_b2[0][i] = dr_b2[i]; s_b2[1][i] = di_b2[i]; }
  if (t >= 384 && t < 512) s_rob1[t - 384] = ro_b1[t - 384];
  if (t >= 512 && t < 576) s_b3d[t - 512] = dr_b3[t - 512];
  if (t >= 576 && t < 608) s_rob2[t - 576] = ro_b2[t - 576];
  s_b3g[t] = di_b3[t];
  if (t < 64) s_dwn[t >> 4][t & 15] = 0.f;

  // ---- init: y0 = init_noise @ embT + emb_b ----
  if (t < 256) {
    const int r = t >> 6, o = t & 63;
    const float* __restrict__ inr = init_noise + (size_t)(b0 + r) * INOISED;
    float a = emb_b[o];
    #pragma unroll 8
    for (int i = 0; i < INOISED; ++i) a = fmaf(inr[i], wsf[EMBT + i * 64 + o], a);
    s_y[r][o] = a; s_z[r][o] = a; s_f[r][o] = 0.f; s_v[r][o] = 0.f;
  }
  __syncthreads();

  const int net = t >> 9;            // 0 = drift, 1 = diffusion
  const int q2  = (t >> 7) & 3;      // K-quarter / row-group
  const int oo  = t & 127;           // output index

  for (int k = 0; k < TT; ++k) {
    const float tval = s_ts[k];

    // ==== L1: 65 -> 128 both nets, 4-way K-split ====
    {
      const uint32_t* __restrict__ Wp = wsu + (net ? GW1P : DW1P);
      float a0, a1, a2, a3;
      if (q2 == 0) {
        const float w0 = wsf[(net ? GW1R0 : DW1R0) + oo];
        a0 = w0 * tval; a1 = a0; a2 = a0; a3 = a0;
      } else { a0 = a1 = a2 = a3 = 0.f; }
      const int p0 = q2 * 8;
      #pragma unroll
      for (int j = 0; j < 8; ++j) {
        const int p = p0 + j;
        const uint32_t w = Wp[p * HIDD + oo];
        const float wl = bflo(w), wh = bfhi(w);
        const float2 z0 = *(const float2*)&s_z[0][2*p];
        const float2 z1 = *(const float2*)&s_z[1][2*p];
        const float2 z2 = *(const float2*)&s_z[2][2*p];
        const float2 z3 = *(const float2*)&s_z[3][2*p];
        a0 = fmaf(z0.x, wl, a0); a0 = fmaf(z0.y, wh, a0);
        a1 = fmaf(z1.x, wl, a1); a1 = fmaf(z1.y, wh, a1);
        a2 = fmaf(z2.x, wl, a2); a2 = fmaf(z2.y, wh, a2);
        a3 = fmaf(z3.x, wl, a3); a3 = fmaf(z3.y, wh, a3);
      }
      float* pb = s_p + ((net*4 + q2)*4) * HIDD + oo;
      pb[0] = a0; pb[HIDD] = a1; pb[2*HIDD] = a2; pb[3*HIDD] = a3;
    }
    __syncthreads();

    // ==== c1: combine + lipswish; rotate noise ====
    {
      float x = s_b1[net][oo];
      #pragma unroll
      for (int qq = 0; qq < 4; ++qq) x += s_p[((net*4 + qq)*4 + q2) * HIDD + oo];
      s_h1[net][q2][oo] = lipswish(x);
      if (t < 64) {
        const int r = t >> 4, n = t & 15;
        const float tmp = s_dwn[r][n];
        float nv = 0.f;
        if (k < TT - 1) nv = bm[((size_t)k * NBATCH + b0 + r) * NOISED + n] * sqrtf(s_ts[k+1] - s_ts[k]);
        s_dwn[r][n] = nv;
        s_dwi[r][n] = tmp;
      }
    }
    __syncthreads();

    // ==== L2: 128 -> 128 both nets, 4-way K-split ====
    {
      const uint32_t* __restrict__ Wp = wsu + (net ? GW2P : DW2P);
      float a0 = 0.f, a1 = 0.f, a2 = 0.f, a3 = 0.f;
      const int p0 = q2 * 16;
      #pragma unroll
      for (int j = 0; j < 16; ++j) {
        const int p = p0 + j;
        const uint32_t w = Wp[p * HIDD + oo];
        const float wl = bflo(w), wh = bfhi(w);
        const float2 h0 = *(const float2*)&s_h1[net][0][2*p];
        const float2 h1 = *(const float2*)&s_h1[net][1][2*p];
        const float2 h2 = *(const float2*)&s_h1[net][2][2*p];
        const float2 h3 = *(const float2*)&s_h1[net][3][2*p];
        a0 = fmaf(h0.x, wl, a0); a0 = fmaf(h0.y, wh, a0);
        a1 = fmaf(h1.x, wl, a1); a1 = fmaf(h1.y, wh, a1);
        a2 = fmaf(h2.x, wl, a2); a2 = fmaf(h2.y, wh, a2);
        a3 = fmaf(h3.x, wl, a3); a3 = fmaf(h3.y, wh, a3);
      }
      float* pb = s_p + ((net*4 + q2)*4) * HIDD + oo;
      pb[0] = a0; pb[HIDD] = a1; pb[2*HIDD] = a2; pb[3*HIDD] = a3;
    }
    __syncthreads();

    // ==== c2 ====
    {
      float x = s_b2[net][oo];
      #pragma unroll
      for (int qq = 0; qq < 4; ++qq) x += s_p[((net*4 + qq)*4 + q2) * HIDD + oo];
      s_h2[net][q2][oo] = lipswish(x);
    }
    __syncthreads();

    // ==== L3g (all 1024: one col each, bias folded, dual noise contraction) + phD (t<512) ====
    {
      float a0 = 0.f, a1 = 0.f, a2 = 0.f, a3 = 0.f;
      const uint32_t* __restrict__ Wg = wsu + GW3P + t;
      #pragma unroll 8
      for (int p = 0; p < 64; ++p) {
        const uint32_t w = Wg[p * 1024];
        const float wl = bflo(w), wh = bfhi(w);
        const float2 h0 = *(const float2*)&s_h2[1][0][2*p];
        const float2 h1 = *(const float2*)&s_h2[1][1][2*p];
        const float2 h2 = *(const float2*)&s_h2[1][2][2*p];
        const float2 h3 = *(const float2*)&s_h2[1][3][2*p];
        a0 = fmaf(h0.x, wl, a0); a0 = fmaf(h0.y, wh, a0);
        a1 = fmaf(h1.x, wl, a1); a1 = fmaf(h1.y, wh, a1);
        a2 = fmaf(h2.x, wl, a2); a2 = fmaf(h2.y, wh, a2);
        a3 = fmaf(h3.x, wl, a3); a3 = fmaf(h3.y, wh, a3);
      }
      const float bg = s_b3g[t];
      a0 += bg; a1 += bg; a2 += bg; a3 += bg;
      const int n = t & 15, l = t >> 4;
      float u0 = a0 * s_dwi[0][n], u1 = a1 * s_dwi[1][n], u2 = a2 * s_dwi[2][n], u3 = a3 * s_dwi[3][n];
      float v0 = a0 * s_dwn[0][n], v1 = a1 * s_dwn[1][n], v2 = a2 * s_dwn[2][n], v3 = a3 * s_dwn[3][n];
      #pragma unroll
      for (int d = 1; d < 16; d <<= 1) {
        u0 += __shfl_xor(u0, d); u1 += __shfl_xor(u1, d);
        u2 += __shfl_xor(u2, d); u3 += __shfl_xor(u3, d);
        v0 += __shfl_xor(v0, d); v1 += __shfl_xor(v1, d);
        v2 += __shfl_xor(v2, d); v3 += __shfl_xor(v3, d);
      }
      if (n == 0) {
        s_u[0][l] = u0; s_u[1][l] = u1; s_u[2][l] = u2; s_u[3][l] = u3;
        s_vn[0][l] = v0; s_vn[1][l] = v1; s_vn[2][l] = v2; s_vn[3][l] = v3;
      }
    }
    if (t < 512) {
      const int qd = t >> 6, od = t & 63;
      float a0 = 0.f, a1 = 0.f, a2 = 0.f, a3 = 0.f;
      #pragma unroll
      for (int j = 0; j < 8; ++j) {
        const int p = qd * 8 + j;
        const uint32_t w = wsu[DW3P + p * 64 + od];
        const float wl = bflo(w), wh = bfhi(w);
        const float2 h0 = *(const float2*)&s_h2[0][0][2*p];
        const float2 h1 = *(const float2*)&s_h2[0][1][2*p];
        const float2 h2 = *(const float2*)&s_h2[0][2][2*p];
        const float2 h3 = *(const float2*)&s_h2[0][3][2*p];
        a0 = fmaf(h0.x, wl, a0); a0 = fmaf(h0.y, wh, a0);
        a1 = fmaf(h1.x, wl, a1); a1 = fmaf(h1.y, wh, a1);
        a2 = fmaf(h2.x, wl, a2); a2 = fmaf(h2.y, wh, a2);
        a3 = fmaf(h3.x, wl, a3); a3 = fmaf(h3.y, wh, a3);
      }
      s_pd[qd][0][od] = a0; s_pd[qd][1][od] = a1; s_pd[qd][2][od] = a2; s_pd[qd][3][od] = a3;
    }
    __syncthreads();

    // ==== upd: Heun update + rotate state ====
    if (t < 256) {
      const int r = t >> 6, o = t & 63;
      float f1 = s_b3d[o];
      #pragma unroll
      for (int qd = 0; qd < 8; ++qd) f1 += s_pd[qd][r][o];
      const float u1 = s_u[r][o], v1 = s_vn[r][o];
      const float dti = (k > 0) ? (s_ts[k] - s_ts[k-1]) : 0.f;
      const float dtn = (k < TT-1) ? (s_ts[k+1] - s_ts[k]) : 0.f;
      const float y1 = s_y[r][o] + 0.5f*(s_f[r][o] + f1)*dti + 0.5f*(s_v[r][o] + u1);
      const float z1 = 2.f*y1 - s_z[r][o] + f1*dtn + v1;
      s_y[r][o] = y1; s_z[r][o] = z1; s_f[r][o] = f1; s_v[r][o] = v1;
      s_ybuf[k & 7][r][o] = y1;
    }
    __syncthreads();

    // ==== batched readout every 8 steps ====
    if ((k & 7) == 7) {
      {
        const int tg4 = t >> 7;   // token group of 4
        float acc[4];
        #pragma unroll
        for (int jt = 0; jt < 4; ++jt) acc[jt] = s_rob1[oo];
        #pragma unroll 8
        for (int p = 0; p < 32; ++p) {
          const uint32_t w = wsu[RO1P + p * 128 + oo];
          const float wl = bflo(w), wh = bfhi(w);
          #pragma unroll
          for (int jt = 0; jt < 4; ++jt) {
            const int tok = tg4 * 4 + jt;
            const float2 y2 = *(const float2*)&s_ybuf[tok >> 2][tok & 3][2*p];
            acc[jt] = fmaf(y2.x, wl, acc[jt]);
            acc[jt] = fmaf(y2.y, wh, acc[jt]);
          }
        }
        #pragma unroll
        for (int jt = 0; jt < 4; ++jt)
          s_p[(size_t)(tg4 * 4 + jt) * HIDD + oo] = lipswish(acc[jt]);
      }
      __syncthreads();
      {
        const int tok = t >> 5, o = t & 31;
        float a = s_rob2[o];
        #pragma unroll 8
        for (int p = 0; p < 64; ++p) {
          const uint32_t w = wsu[RO2P + p * 32 + o];
          const float2 h2 = *(const float2*)&s_p[(size_t)tok * HIDD + 2*p];
          a = fmaf(h2.x, bflo(w), a);
          a = fmaf(h2.y, bfhi(w), a);
        }
        const int kk = tok >> 2, r = tok & 3;
        const int tg = k - 7 + kk;
        out[((size_t)(b0 + r) * TT + tg) * OUTD + o] = a;
        if (mult > 0 && (tg % mult) == 0) {
          const int jj = tg / mult;
          if (jj < steps)
            out[(size_t)NBATCH * TT * OUTD + ((size_t)(b0 + r) * steps + jj) * OUTD + o] = a;
        }
      }
      __syncthreads();
    }
  }
}

extern "C" void kernel_launch(void* const* d_in, const int* in_sizes, int n_in,
                              void* d_out, int out_size, void* d_ws, size_t ws_size,
                              hipStream_t stream) {
  (void)in_sizes; (void)n_in; (void)out_size; (void)ws_size;
  const float* init_noise = (const float*)d_in[0];
  const float* bm_noise   = (const float*)d_in[1];
  const float* ts         = (const float*)d_in[2];
  const int*   p_steps    = (const int*)d_in[3];
  const int*   p_mult     = (const int*)d_in[4];
  const float* emb_W = (const float*)d_in[5];
  const float* emb_b = (const float*)d_in[6];
  const float* dr_v1 = (const float*)d_in[7];
  const float* dr_g1 = (const float*)d_in[8];
  const float* dr_b1 = (const float*)d_in[9];
  const float* dr_v2 = (const float*)d_in[10];
  const float* dr_g2 = (const float*)d_in[11];
  const float* dr_b2 = (const float*)d_in[12];
  const float* dr_v3 = (const float*)d_in[13];
  const float* dr_g3 = (const float*)d_in[14];
  const float* dr_b3 = (const float*)d_in[15];
  const float* di_v1 = (const float*)d_in[16];
  const float* di_g1 = (const float*)d_in[17];
  const float* di_b1 = (const float*)d_in[18];
  const float* di_v2 = (const float*)d_in[19];
  const float* di_g2 = (const float*)d_in[20];
  const float* di_b2 = (const float*)d_in[21];
  const float* di_v3 = (const float*)d_in[22];
  const float* di_g3 = (const float*)d_in[23];
  const float* di_b3 = (const float*)d_in[24];
  const float* ro_W1 = (const float*)d_in[25];
  const float* ro_b1 = (const float*)d_in[26];
  const float* ro_W2 = (const float*)d_in[27];
  const float* ro_b2 = (const float*)d_in[28];
  float* ws = (float*)d_ws;
  float* out = (float*)d_out;

  prep_kernel<<<dim3(1024, 9), 128, 0, stream>>>(
      dr_v1, dr_g1, dr_v2, dr_g2, dr_v3, dr_g3,
      di_v1, di_g1, di_v2, di_g2, di_v3, di_g3,
      emb_W, ro_W1, ro_W2, ws);

  sde_main<<<256, 1024, 0, stream>>>(
      init_noise, bm_noise, ts, p_steps, p_mult,
      emb_b, dr_b1, dr_b2, dr_b3, di_b1, di_b2, di_b3,
      ro_b1, ro_b2, ws, out);
}

// Round 4
// 2005.226 us; speedup vs baseline: 1.2271x; 1.2271x over previous
//
#include <hip/hip_runtime.h>
#include <hip/hip_bf16.h>
#include <math.h>

typedef unsigned int u32;
typedef unsigned short u16;
typedef __attribute__((ext_vector_type(8))) short bf16x8;
typedef __attribute__((ext_vector_type(4))) float f32x4;

#define NBATCH 1024
#define TT 128
#define NB 16
#define NBLK 64
#define OUTD 32

// ---- ws layout: u16 fragment arrays then f32 region ----
#define F_DW1 0
#define F_GW1 8192
#define F_DW2 16384
#define F_GW2 32768
#define F_DW3 49152
#define F_GW3 57344
#define F_RO1 188416
#define F_RO2 196608
#define U16_END 200704
// f32 region (index into wsf = (float*)(wsu + U16_END))
#define FW_EMB 0
#define FW_W0D 4096
#define FW_W0G 4224

__device__ __forceinline__ float lipswish(float x) {
  return 0.909f * x / (1.0f + expf(-x));
}
__device__ __forceinline__ u32 bf16r(float x) {
  u32 u = __float_as_uint(x);
  return ((u + 0x7fffu + ((u >> 16) & 1u)) >> 16) & 0xffffu;
}

// ---------------- prep: weight-norm + bf16 fragment-layout pack ----------------
__global__ void prep_kernel(const float* dr_v1, const float* dr_g1,
                            const float* dr_v2, const float* dr_g2,
                            const float* dr_v3, const float* dr_g3,
                            const float* di_v1, const float* di_g1,
                            const float* di_v2, const float* di_g2,
                            const float* di_v3, const float* di_g3,
                            const float* emb_W, const float* ro_W1, const float* ro_W2,
                            float* ws) {
  __shared__ float sred[2];
  u16* wsu = (u16*)ws;
  float* wsf = (float*)(wsu + U16_END);
  const int mat = blockIdx.y;
  const int row = blockIdx.x;
  const int i = threadIdx.x;
  const float* v = nullptr; const float* g = nullptr;
  int rows = 0, len = 0, O = 0; long F = -1; int l1 = 0; int w0 = 0;
  switch (mat) {
    case 0: v = dr_v1; g = dr_g1; rows = 128;  len = 65;  O = 128;  F = F_DW1; l1 = 1; w0 = FW_W0D; break;
    case 1: v = dr_v2; g = dr_g2; rows = 128;  len = 128; O = 128;  F = F_DW2; break;
    case 2: v = dr_v3; g = dr_g3; rows = 64;   len = 128; O = 64;   F = F_DW3; break;
    case 3: v = di_v1; g = di_g1; rows = 128;  len = 65;  O = 128;  F = F_GW1; l1 = 1; w0 = FW_W0G; break;
    case 4: v = di_v2; g = di_g2; rows = 128;  len = 128; O = 128;  F = F_GW2; break;
    case 5: v = di_v3; g = di_g3; rows = 1024; len = 128; O = 1024; F = F_GW3; break;
    case 6: v = emb_W; g = nullptr; rows = 64;  len = 64;  break;
    case 7: v = ro_W1; g = nullptr; rows = 128; len = 64;  O = 128; F = F_RO1; break;
    case 8: v = ro_W2; g = nullptr; rows = 32;  len = 128; O = 32;  F = F_RO2; break;
  }
  if (row >= rows) return;
  const float x = (i < len) ? v[(size_t)row * len + i] : 0.0f;
  float scale = 1.0f;
  if (g != nullptr) {
    float ss = x * x;
    #pragma unroll
    for (int d = 1; d < 64; d <<= 1) ss += __shfl_xor(ss, d);
    if ((i & 63) == 0) sred[i >> 6] = ss;
    __syncthreads();
    scale = g[row] / sqrtf(sred[0] + sred[1]);
  }
  const float xs = x * scale;
  if (mat == 6) {                       // embT f32 [i][o]
    if (i < len) wsf[FW_EMB + i * 64 + row] = xs;
    return;
  }
  if (l1) {
    if (i == 0) wsf[w0 + row] = xs;     // t-row stays f32
    if (i >= 1 && i < len) {
      const int kk = i - 1;
      wsu[F + ((size_t)((kk >> 3) * O + row)) * 8 + (kk & 7)] = (u16)bf16r(xs);
    }
  } else if (i < len) {
    wsu[F + ((size_t)((i >> 3) * O + row)) * 8 + (i & 7)] = (u16)bf16r(xs);
  }
}

// ---- A-fragment build: split f32 -> bf16 hi + bf16 lo ----
template<int KTS>
__device__ __forceinline__ void build_a(const float* base, int stride, int c, int g,
                                        bf16x8* hi, bf16x8* lo) {
  #pragma unroll
  for (int kt = 0; kt < KTS; ++kt) {
    const float* p = base + c * stride + kt * 32 + g * 8;
    const float4 x0 = *(const float4*)p;
    const float4 x1 = *(const float4*)(p + 4);
    const float xs[8] = {x0.x, x0.y, x0.z, x0.w, x1.x, x1.y, x1.z, x1.w};
    bf16x8 h, l;
    #pragma unroll
    for (int j = 0; j < 8; ++j) {
      __hip_bfloat16 bh = __float2bfloat16(xs[j]);
      const float hf = __bfloat162float(bh);
      __hip_bfloat16 bl = __float2bfloat16(xs[j] - hf);
      h[j] = *reinterpret_cast<short*>(&bh);
      l[j] = *reinterpret_cast<short*>(&bl);
    }
    hi[kt] = h; lo[kt] = l;
  }
}

// ---- one 16x16 output tile, K = KTS*32, split-A double MFMA ----
template<int KTS>
__device__ __forceinline__ f32x4 mm_tile(const u16* W, int O, int col, int g,
                                         const bf16x8* hi, const bf16x8* lo, float ci) {
  f32x4 acc = {ci, ci, ci, ci};
  #pragma unroll
  for (int kt = 0; kt < KTS; ++kt) {
    const bf16x8 b = *(const bf16x8*)(W + ((size_t)((kt * 4 + g) * O + col)) * 8);
    acc = __builtin_amdgcn_mfma_f32_16x16x32_bf16(hi[kt], b, acc, 0, 0, 0);
    acc = __builtin_amdgcn_mfma_f32_16x16x32_bf16(lo[kt], b, acc, 0, 0, 0);
  }
  return acc;
}

// ---------------- main persistent kernel: 64 blocks x 1024 threads, 16 rows ----------------
__global__ void __launch_bounds__(1024, 4)
sde_main(const float* __restrict__ init_noise, const float* __restrict__ bm,
         const float* __restrict__ ts_g, const int* __restrict__ p_steps,
         const int* __restrict__ p_mult, const float* __restrict__ emb_b,
         const float* __restrict__ dr_b1, const float* __restrict__ dr_b2, const float* __restrict__ dr_b3,
         const float* __restrict__ di_b1, const float* __restrict__ di_b2, const float* __restrict__ di_b3,
         const float* __restrict__ ro_b1, const float* __restrict__ ro_b2,
         const float* __restrict__ ws, float* __restrict__ out)
{
  extern __shared__ float sm[];
  float* s_z   = sm;            // [16][68]
  float* s_h1  = sm + 1088;     // [2][16][132]
  float* s_h2  = sm + 5312;     // [2][16][132]
  float* s_hro = sm + 1088;     // overlay [64][132] (h1+h2 dead during readout)
  float* s_f1  = sm + 9536;     // [16][64]
  float* s_u   = sm + 10560;    // [16][64]
  float* s_v   = sm + 11584;    // [16][64]
  float* s_yb  = sm + 12608;    // [4][16][68]
  float* s_dwi = sm + 16960;    // [16][17]
  float* s_dwn = sm + 17232;    // [16][17]
  float* s_b3g = sm + 17504;    // [1024]
  float* s_w0d = sm + 18528;
  float* s_w0g = sm + 18656;
  float* s_b1d = sm + 18784;
  float* s_b1g = sm + 18912;
  float* s_b2d = sm + 19040;
  float* s_b2g = sm + 19168;
  float* s_b3d = sm + 19296;    // [64]
  float* s_rb1 = sm + 19360;    // [128]
  float* s_rb2 = sm + 19488;    // [32]
  float* s_ts  = sm + 19520;    // [128]

  const int t = threadIdx.x;
  const int b0 = blockIdx.x * NB;
  const u16* __restrict__ wsu = (const u16*)ws;
  const float* __restrict__ wsf = (const float*)(wsu + U16_END);
  const int steps = p_steps[0], mult = p_mult[0];

  // ---- stage constants ----
  s_b3g[t] = di_b3[t];
  if (t < 256) s_dwn[(t >> 4) * 17 + (t & 15)] = 0.f;
  if (t < 128) { s_ts[t] = ts_g[t]; s_w0d[t] = wsf[FW_W0D + t]; s_w0g[t] = wsf[FW_W0G + t]; }
  else if (t < 256) { const int i = t - 128; s_b1d[i] = dr_b1[i]; s_b1g[i] = di_b1[i]; }
  else if (t < 384) { const int i = t - 256; s_b2d[i] = dr_b2[i]; s_b2g[i] = di_b2[i]; }
  else if (t < 512) { s_rb1[t - 384] = ro_b1[t - 384]; }
  else if (t < 576) { s_b3d[t - 512] = dr_b3[t - 512]; }
  else if (t < 608) { s_rb2[t - 576] = ro_b2[t - 576]; }

  // ---- init: y0 = init_noise @ embT + emb_b; state in owner regs ----
  float y_reg, z_reg, f_reg = 0.f, v_reg = 0.f;
  {
    const int r = t >> 6, o = t & 63;
    const float* __restrict__ inr = init_noise + (size_t)(b0 + r) * 64;
    float a = emb_b[o];
    #pragma unroll 8
    for (int i = 0; i < 64; ++i) a = fmaf(inr[i], wsf[FW_EMB + i * 64 + o], a);
    y_reg = a; z_reg = a;
    s_z[r * 68 + o] = a;
  }
  __syncthreads();

  const int w = t >> 6;          // wave id 0..15
  const int lane = t & 63;
  const int g = lane >> 4;       // k-octet group
  const int c = lane & 15;       // col / A-row index

  for (int k = 0; k < TT; ++k) {
    const float tval = s_ts[k];

    // ==== phase 1: L1 (65->128), drift waves 0-7, diffusion waves 8-15 ====
    {
      const int net = w >> 3, nt = w & 7;
      bf16x8 ahi[2], alo[2];
      build_a<2>(s_z, 68, c, g, ahi, alo);
      const int col = nt * 16 + c;
      const float ci = net ? (tval * s_w0g[col] + s_b1g[col])
                           : (tval * s_w0d[col] + s_b1d[col]);
      f32x4 acc = mm_tile<2>(wsu + (net ? F_GW1 : F_DW1), 128, col, g, ahi, alo, ci);
      float* h1 = s_h1 + net * 16 * 132;
      #pragma unroll
      for (int j = 0; j < 4; ++j) h1[(g * 4 + j) * 132 + col] = lipswish(acc[j]);
      if (t < 256) {               // noise increment rotation
        const int rr = t >> 4, nn = t & 15;
        const int di = rr * 17 + nn;
        const float old = s_dwn[di];
        s_dwi[di] = old;
        float nv = 0.f;
        if (k < TT - 1)
          nv = bm[((size_t)k * NBATCH + b0 + rr) * 16 + nn] * sqrtf(s_ts[k + 1] - tval);
        s_dwn[di] = nv;
      }
    }
    __syncthreads();

    // ==== phase 2: L2 (128->128) both nets ====
    {
      const int net = w >> 3, nt = w & 7;
      bf16x8 ahi[4], alo[4];
      build_a<4>(s_h1 + net * 16 * 132, 132, c, g, ahi, alo);
      const int col = nt * 16 + c;
      const float ci = net ? s_b2g[col] : s_b2d[col];
      f32x4 acc = mm_tile<4>(wsu + (net ? F_GW2 : F_DW2), 128, col, g, ahi, alo, ci);
      float* h2 = s_h2 + net * 16 * 132;
      #pragma unroll
      for (int j = 0; j < 4; ++j) h2[(g * 4 + j) * 132 + col] = lipswish(acc[j]);
    }
    __syncthreads();

    // ==== phase 3: gW3 (128->1024) + dual noise contraction; drift L3 on waves 12-15 ====
    {
      bf16x8 ahi[4], alo[4];
      build_a<4>(s_h2 + 16 * 132, 132, c, g, ahi, alo);   // diffusion h2
      #pragma unroll
      for (int j4 = 0; j4 < 4; ++j4) {
        const int l = w * 4 + j4;                          // latent index 0..63
        f32x4 acc = mm_tile<4>(wsu + F_GW3, 1024, l * 16 + c, g, ahi, alo, s_b3g[l * 16 + c]);
        float up[4], vp[4];
        #pragma unroll
        for (int j = 0; j < 4; ++j) {
          const int m = g * 4 + j;
          up[j] = acc[j] * s_dwi[m * 17 + c];
          vp[j] = acc[j] * s_dwn[m * 17 + c];
        }
        #pragma unroll
        for (int d = 1; d < 16; d <<= 1) {
          #pragma unroll
          for (int j = 0; j < 4; ++j) {
            up[j] += __shfl_xor(up[j], d);
            vp[j] += __shfl_xor(vp[j], d);
          }
        }
        if (c == 0) {
          #pragma unroll
          for (int j = 0; j < 4; ++j) {
            s_u[(g * 4 + j) * 64 + l] = up[j];
            s_v[(g * 4 + j) * 64 + l] = vp[j];
          }
        }
      }
      if (w >= 12) {               // drift L3: N-tile w-12
        const int nt = w - 12;
        bf16x8 dhi[4], dlo[4];
        build_a<4>(s_h2, 132, c, g, dhi, dlo);
        const int col = nt * 16 + c;
        f32x4 acc = mm_tile<4>(wsu + F_DW3, 64, col, g, dhi, dlo, s_b3d[col]);
        #pragma unroll
        for (int j = 0; j < 4; ++j) s_f1[(g * 4 + j) * 64 + col] = acc[j];
      }
    }
    __syncthreads();

    // ==== phase 4: Heun update (owner thread per (row, latent)) ====
    {
      const int r = w, o = lane;
      const float f1 = s_f1[r * 64 + o];
      const float u1 = s_u[r * 64 + o];
      const float v1 = s_v[r * 64 + o];
      const float dti = (k > 0) ? (tval - s_ts[k - 1]) : 0.f;
      const float dtn = (k < TT - 1) ? (s_ts[k + 1] - tval) : 0.f;
      y_reg = y_reg + 0.5f * (f_reg + f1) * dti + 0.5f * (v_reg + u1);
      z_reg = 2.f * y_reg - z_reg + f1 * dtn + v1;
      f_reg = f1; v_reg = v1;
      s_z[r * 68 + o] = z_reg;
      s_yb[(k & 3) * 1088 + r * 68 + o] = y_reg;
    }
    __syncthreads();

    // ==== batched readout every 4 steps: 64 tokens ====
    if ((k & 3) == 3) {
      #pragma unroll
      for (int tt2 = 0; tt2 < 2; ++tt2) {   // ro1: 32 tiles over 16 waves
        const int T = w + tt2 * 16;
        const int st = T >> 3, nt = T & 7;
        bf16x8 ahi[2], alo[2];
        build_a<2>(s_yb + st * 1088, 68, c, g, ahi, alo);
        const int col = nt * 16 + c;
        f32x4 acc = mm_tile<2>(wsu + F_RO1, 128, col, g, ahi, alo, s_rb1[col]);
        #pragma unroll
        for (int j = 0; j < 4; ++j)
          s_hro[(st * 16 + g * 4 + j) * 132 + col] = lipswish(acc[j]);
      }
      __syncthreads();
      if (w < 8) {                          // ro2: 8 tiles
        const int mt = w >> 1, nt = w & 1;
        bf16x8 ahi[4], alo[4];
        build_a<4>(s_hro + mt * 16 * 132, 132, c, g, ahi, alo);
        const int col = nt * 16 + c;
        f32x4 acc = mm_tile<4>(wsu + F_RO2, 32, col, g, ahi, alo, s_rb2[col]);
        const int tg = k - 3 + mt;
        #pragma unroll
        for (int j = 0; j < 4; ++j) {
          const int r = g * 4 + j;
          out[((size_t)(b0 + r) * TT + tg) * OUTD + col] = acc[j];
          if (mult > 0 && (tg % mult) == 0) {
            const int jj = tg / mult;
            if (jj < steps)
              out[(size_t)NBATCH * TT * OUTD + ((size_t)(b0 + r) * steps + jj) * OUTD + col] = acc[j];
          }
        }
      }
      __syncthreads();
    }
  }
}

extern "C" void kernel_launch(void* const* d_in, const int* in_sizes, int n_in,
                              void* d_out, int out_size, void* d_ws, size_t ws_size,
                              hipStream_t stream) {
  (void)in_sizes; (void)n_in; (void)out_size; (void)ws_size;
  const float* init_noise = (const float*)d_in[0];
  const float* bm_noise   = (const float*)d_in[1];
  const float* ts         = (const float*)d_in[2];
  const int*   p_steps    = (const int*)d_in[3];
  const int*   p_mult     = (const int*)d_in[4];
  const float* emb_W = (const float*)d_in[5];
  const float* emb_b = (const float*)d_in[6];
  const float* dr_v1 = (const float*)d_in[7];
  const float* dr_g1 = (const float*)d_in[8];
  const float* dr_b1 = (const float*)d_in[9];
  const float* dr_v2 = (const float*)d_in[10];
  const float* dr_g2 = (const float*)d_in[11];
  const float* dr_b2 = (const float*)d_in[12];
  const float* dr_v3 = (const float*)d_in[13];
  const float* dr_g3 = (const float*)d_in[14];
  const float* dr_b3 = (const float*)d_in[15];
  const float* di_v1 = (const float*)d_in[16];
  const float* di_g1 = (const float*)d_in[17];
  const float* di_b1 = (const float*)d_in[18];
  const float* di_v2 = (const float*)d_in[19];
  const float* di_g2 = (const float*)d_in[20];
  const float* di_b2 = (const float*)d_in[21];
  const float* di_v3 = (const float*)d_in[22];
  const float* di_g3 = (const float*)d_in[23];
  const float* di_b3 = (const float*)d_in[24];
  const float* ro_W1 = (const float*)d_in[25];
  const float* ro_b1 = (const float*)d_in[26];
  const float* ro_W2 = (const float*)d_in[27];
  const float* ro_b2 = (const float*)d_in[28];
  float* ws = (float*)d_ws;
  float* out = (float*)d_out;

  (void)hipFuncSetAttribute((const void*)sde_main,
                            hipFuncAttributeMaxDynamicSharedMemorySize, 160 * 1024);

  prep_kernel<<<dim3(1024, 9), 128, 0, stream>>>(
      dr_v1, dr_g1, dr_v2, dr_g2, dr_v3, dr_g3,
      di_v1, di_g1, di_v2, di_g2, di_v3, di_g3,
      emb_W, ro_W1, ro_W2, ws);

  sde_main<<<NBLK, 1024, 78592 * sizeof(float) / sizeof(float), stream>>>(
      init_noise, bm_noise, ts, p_steps, p_mult,
      emb_b, dr_b1, dr_b2, dr_b3, di_b1, di_b2, di_b3,
      ro_b1, ro_b2, ws, out);
}

// Round 5
// 1789.537 us; speedup vs baseline: 1.3750x; 1.1205x over previous
//
#include <hip/hip_runtime.h>
#include <hip/hip_bf16.h>
#include <math.h>

typedef unsigned int u32;
typedef unsigned short u16;
typedef __attribute__((ext_vector_type(8))) short bf16x8;
typedef __attribute__((ext_vector_type(4))) float f32x4;

#define NBATCH 1024
#define TT 128
#define NB 16
#define NBLK 64
#define OUTD 32

// ---- ws layout: u16 fragment arrays then f32 region (same as round 4) ----
#define F_DW1 0
#define F_GW1 8192
#define F_DW2 16384
#define F_GW2 32768
#define F_DW3 49152
#define F_GW3 57344
#define F_RO1 188416
#define F_RO2 196608
#define U16_END 200704
#define FW_EMB 0
#define FW_W0D 4096
#define FW_W0G 4224

__device__ __forceinline__ float lipswish(float x) {
  return 0.909f * x / (1.0f + expf(-x));
}
__device__ __forceinline__ u32 bf16r(float x) {
  u32 u = __float_as_uint(x);
  return ((u + 0x7fffu + ((u >> 16) & 1u)) >> 16) & 0xffffu;
}

// ---------------- prep: weight-norm + bf16 fragment-layout pack ----------------
__global__ void prep_kernel(const float* dr_v1, const float* dr_g1,
                            const float* dr_v2, const float* dr_g2,
                            const float* dr_v3, const float* dr_g3,
                            const float* di_v1, const float* di_g1,
                            const float* di_v2, const float* di_g2,
                            const float* di_v3, const float* di_g3,
                            const float* emb_W, const float* ro_W1, const float* ro_W2,
                            float* ws) {
  __shared__ float sred[2];
  u16* wsu = (u16*)ws;
  float* wsf = (float*)(wsu + U16_END);
  const int mat = blockIdx.y;
  const int row = blockIdx.x;
  const int i = threadIdx.x;
  const float* v = nullptr; const float* g = nullptr;
  int rows = 0, len = 0, O = 0; long F = -1; int l1 = 0; int w0 = 0;
  switch (mat) {
    case 0: v = dr_v1; g = dr_g1; rows = 128;  len = 65;  O = 128;  F = F_DW1; l1 = 1; w0 = FW_W0D; break;
    case 1: v = dr_v2; g = dr_g2; rows = 128;  len = 128; O = 128;  F = F_DW2; break;
    case 2: v = dr_v3; g = dr_g3; rows = 64;   len = 128; O = 64;   F = F_DW3; break;
    case 3: v = di_v1; g = di_g1; rows = 128;  len = 65;  O = 128;  F = F_GW1; l1 = 1; w0 = FW_W0G; break;
    case 4: v = di_v2; g = di_g2; rows = 128;  len = 128; O = 128;  F = F_GW2; break;
    case 5: v = di_v3; g = di_g3; rows = 1024; len = 128; O = 1024; F = F_GW3; break;
    case 6: v = emb_W; g = nullptr; rows = 64;  len = 64;  break;
    case 7: v = ro_W1; g = nullptr; rows = 128; len = 64;  O = 128; F = F_RO1; break;
    case 8: v = ro_W2; g = nullptr; rows = 32;  len = 128; O = 32;  F = F_RO2; break;
  }
  if (row >= rows) return;
  const float x = (i < len) ? v[(size_t)row * len + i] : 0.0f;
  float scale = 1.0f;
  if (g != nullptr) {
    float ss = x * x;
    #pragma unroll
    for (int d = 1; d < 64; d <<= 1) ss += __shfl_xor(ss, d);
    if ((i & 63) == 0) sred[i >> 6] = ss;
    __syncthreads();
    scale = g[row] / sqrtf(sred[0] + sred[1]);
  }
  const float xs = x * scale;
  if (mat == 6) {
    if (i < len) wsf[FW_EMB + i * 64 + row] = xs;
    return;
  }
  if (l1) {
    if (i == 0) wsf[w0 + row] = xs;
    if (i >= 1 && i < len) {
      const int kk = i - 1;
      wsu[F + ((size_t)((kk >> 3) * O + row)) * 8 + (kk & 7)] = (u16)bf16r(xs);
    }
  } else if (i < len) {
    wsu[F + ((size_t)((i >> 3) * O + row)) * 8 + (i & 7)] = (u16)bf16r(xs);
  }
}

// ---- A-fragment build: split f32 -> bf16 hi + bf16 lo ----
template<int KTS>
__device__ __forceinline__ void build_a(const float* base, int stride, int c, int g,
                                        bf16x8* hi, bf16x8* lo) {
  #pragma unroll
  for (int kt = 0; kt < KTS; ++kt) {
    const float* p = base + c * stride + kt * 32 + g * 8;
    const float4 x0 = *(const float4*)p;
    const float4 x1 = *(const float4*)(p + 4);
    const float xs[8] = {x0.x, x0.y, x0.z, x0.w, x1.x, x1.y, x1.z, x1.w};
    bf16x8 h, l;
    #pragma unroll
    for (int j = 0; j < 8; ++j) {
      __hip_bfloat16 bh = __float2bfloat16(xs[j]);
      const float hf = __bfloat162float(bh);
      __hip_bfloat16 bl = __float2bfloat16(xs[j] - hf);
      h[j] = *reinterpret_cast<short*>(&bh);
      l[j] = *reinterpret_cast<short*>(&bl);
    }
    hi[kt] = h; lo[kt] = l;
  }
}

__device__ __forceinline__ f32x4 mfma2(bf16x8 hi, bf16x8 lo, bf16x8 b, f32x4 acc) {
  acc = __builtin_amdgcn_mfma_f32_16x16x32_bf16(hi, b, acc, 0, 0, 0);
  acc = __builtin_amdgcn_mfma_f32_16x16x32_bf16(lo, b, acc, 0, 0, 0);
  return acc;
}

// ---------------- main persistent kernel: 64 blocks x 512 threads (8 waves), 16 rows ----------------
__global__ void __launch_bounds__(512, 2)
sde_main(const float* __restrict__ init_noise, const float* __restrict__ bm,
         const float* __restrict__ ts_g, const int* __restrict__ p_steps,
         const int* __restrict__ p_mult, const float* __restrict__ emb_b,
         const float* __restrict__ dr_b1, const float* __restrict__ dr_b2, const float* __restrict__ dr_b3,
         const float* __restrict__ di_b1, const float* __restrict__ di_b2, const float* __restrict__ di_b3,
         const float* __restrict__ ro_b1, const float* __restrict__ ro_b2,
         const float* __restrict__ ws, float* __restrict__ out)
{
  extern __shared__ float sm[];
  float* s_z   = sm;            // [16][68]
  float* s_h1  = sm + 1088;     // [2][16][132]
  float* s_h2  = sm + 5312;     // [2][16][132]
  float* s_hro = sm + 1088;     // overlay [64][132]
  float* s_f1  = sm + 9536;     // [16][64]
  float* s_u   = sm + 10560;    // [16][64]
  float* s_v   = sm + 11584;    // [16][64]
  float* s_yb  = sm + 12608;    // [4][16][68]
  float* s_dwi = sm + 16960;    // [16][17]
  float* s_dwn = sm + 17232;    // [16][17]
  float* s_b3g = sm + 17504;    // [1024]
  float* s_w0d = sm + 18528;
  float* s_w0g = sm + 18656;
  float* s_b1d = sm + 18784;
  float* s_b1g = sm + 18912;
  float* s_b2d = sm + 19040;
  float* s_b2g = sm + 19168;
  float* s_b3d = sm + 19296;    // [64]
  float* s_rb1 = sm + 19360;    // [128]
  float* s_rb2 = sm + 19488;    // [32]
  float* s_ts  = sm + 19520;    // [128]

  const int t = threadIdx.x;
  const int b0 = blockIdx.x * NB;
  const u16* __restrict__ wsu = (const u16*)ws;
  const float* __restrict__ wsf = (const float*)(wsu + U16_END);
  const int steps = p_steps[0], mult = p_mult[0];

  // ---- stage constants (512 threads) ----
  s_b3g[t] = di_b3[t];
  s_b3g[t + 512] = di_b3[t + 512];
  if (t < 128) { s_ts[t] = ts_g[t]; s_w0d[t] = wsf[FW_W0D + t]; s_w0g[t] = wsf[FW_W0G + t]; }
  else if (t < 256) { const int i = t - 128; s_b1d[i] = dr_b1[i]; s_b1g[i] = di_b1[i]; }
  else if (t < 384) { const int i = t - 256; s_b2d[i] = dr_b2[i]; s_b2g[i] = di_b2[i]; }
  else { const int i = t - 384; s_rb1[i] = ro_b1[i];
         if (i < 64) s_b3d[i] = dr_b3[i];
         else if (i < 96) s_rb2[i - 64] = ro_b2[i - 64]; }
  if (t < 256) s_dwn[(t >> 4) * 17 + (t & 15)] = 0.f;

  // ---- init: y0 = init_noise @ embT + emb_b; owner = (r_own, o_own..o_own+1) ----
  const int r_own = t >> 5;
  const int o_own = (t & 31) * 2;
  float yA, yB, zA, zB, fA = 0.f, fB = 0.f, vA = 0.f, vB = 0.f;
  {
    const float* __restrict__ inr = init_noise + (size_t)(b0 + r_own) * 64;
    float a0 = emb_b[o_own], a1 = emb_b[o_own + 1];
    #pragma unroll 8
    for (int i = 0; i < 64; ++i) {
      const float x = inr[i];
      a0 = fmaf(x, wsf[FW_EMB + i * 64 + o_own], a0);
      a1 = fmaf(x, wsf[FW_EMB + i * 64 + o_own + 1], a1);
    }
    yA = a0; zA = a0; yB = a1; zB = a1;
    s_z[r_own * 68 + o_own] = a0;
    s_z[r_own * 68 + o_own + 1] = a1;
  }
  __syncthreads();

  const int w = t >> 6;          // wave 0..7
  const int lane = t & 63;
  const int g = lane >> 4;       // k-octet group
  const int c = lane & 15;       // A-row / col index
  const int colw = w * 16 + c;   // this wave's N-tile column for L1/L2

  // ---- load resident weight fragments (once) ----
  bf16x8 rw1[2][2], rw2[2][4], rg3[8][4];
  #pragma unroll
  for (int net = 0; net < 2; ++net) {
    #pragma unroll
    for (int kt = 0; kt < 2; ++kt)
      rw1[net][kt] = *(const bf16x8*)(wsu + (net ? F_GW1 : F_DW1) +
                                      ((size_t)((kt * 4 + g) * 128 + colw)) * 8);
    #pragma unroll
    for (int kt = 0; kt < 4; ++kt)
      rw2[net][kt] = *(const bf16x8*)(wsu + (net ? F_GW2 : F_DW2) +
                                      ((size_t)((kt * 4 + g) * 128 + colw)) * 8);
  }
  #pragma unroll
  for (int j4 = 0; j4 < 8; ++j4) {
    const int colg = (w * 8 + j4) * 16 + c;
    #pragma unroll
    for (int kt = 0; kt < 4; ++kt)
      rg3[j4][kt] = *(const bf16x8*)(wsu + F_GW3 +
                                     ((size_t)((kt * 4 + g) * 1024 + colg)) * 8);
  }

  #pragma unroll 1
  for (int k = 0; k < TT; ++k) {
    const float tval = s_ts[k];

    // ==== phase 1: L1 (65->128), each wave: both nets, nt = w ====
    {
      bf16x8 ahi[2], alo[2];
      build_a<2>(s_z, 68, c, g, ahi, alo);
      #pragma unroll
      for (int net = 0; net < 2; ++net) {
        const float ci = net ? fmaf(tval, s_w0g[colw], s_b1g[colw])
                             : fmaf(tval, s_w0d[colw], s_b1d[colw]);
        f32x4 acc = {ci, ci, ci, ci};
        #pragma unroll
        for (int kt = 0; kt < 2; ++kt) acc = mfma2(ahi[kt], alo[kt], rw1[net][kt], acc);
        float* h1 = s_h1 + net * 2112;
        #pragma unroll
        for (int j = 0; j < 4; ++j) h1[(g * 4 + j) * 132 + colw] = lipswish(acc[j]);
      }
      if (t < 256) {   // noise increment rotation
        const int rr = t >> 4, nn = t & 15, di = rr * 17 + nn;
        const float old = s_dwn[di];
        float nv = 0.f;
        if (k < TT - 1)
          nv = bm[((size_t)k * NBATCH + b0 + rr) * 16 + nn] * sqrtf(s_ts[k + 1] - tval);
        s_dwn[di] = nv;
        s_dwi[di] = old;
      }
    }
    __syncthreads();

    // ==== phase 2: L2 (128->128), both nets ====
    {
      #pragma unroll
      for (int net = 0; net < 2; ++net) {
        bf16x8 ahi[4], alo[4];
        build_a<4>(s_h1 + net * 2112, 132, c, g, ahi, alo);
        const float ci = net ? s_b2g[colw] : s_b2d[colw];
        f32x4 acc = {ci, ci, ci, ci};
        #pragma unroll
        for (int kt = 0; kt < 4; ++kt) acc = mfma2(ahi[kt], alo[kt], rw2[net][kt], acc);
        float* h2 = s_h2 + net * 2112;
        #pragma unroll
        for (int j = 0; j < 4; ++j) h2[(g * 4 + j) * 132 + colw] = lipswish(acc[j]);
      }
    }
    __syncthreads();

    // ==== phase 3: dW3 (waves 0-3, L2-streamed B) + gW3 (register B) + noise contraction ====
    {
      if (w < 4) {
        bf16x8 dhi[4], dlo[4];
        build_a<4>(s_h2, 132, c, g, dhi, dlo);          // drift h2
        const int cold = w * 16 + c;
        const float ci = s_b3d[cold];
        f32x4 acc = {ci, ci, ci, ci};
        #pragma unroll
        for (int kt = 0; kt < 4; ++kt) {
          const bf16x8 b = *(const bf16x8*)(wsu + F_DW3 +
                                            ((size_t)((kt * 4 + g) * 64 + cold)) * 8);
          acc = mfma2(dhi[kt], dlo[kt], b, acc);
        }
        #pragma unroll
        for (int j = 0; j < 4; ++j) s_f1[(g * 4 + j) * 64 + cold] = acc[j];
      }
      bf16x8 ahi[4], alo[4];
      build_a<4>(s_h2 + 2112, 132, c, g, ahi, alo);     // diffusion h2
      #pragma unroll
      for (int j4 = 0; j4 < 8; ++j4) {
        const int l = w * 8 + j4;
        const float ci = s_b3g[l * 16 + c];
        f32x4 acc = {ci, ci, ci, ci};
        #pragma unroll
        for (int kt = 0; kt < 4; ++kt) acc = mfma2(ahi[kt], alo[kt], rg3[j4][kt], acc);
        float up[4], vp[4];
        #pragma unroll
        for (int j = 0; j < 4; ++j) {
          const int m = g * 4 + j;
          up[j] = acc[j] * s_dwi[m * 17 + c];
          vp[j] = acc[j] * s_dwn[m * 17 + c];
        }
        #pragma unroll
        for (int d = 1; d < 16; d <<= 1) {
          #pragma unroll
          for (int j = 0; j < 4; ++j) {
            up[j] += __shfl_xor(up[j], d);
            vp[j] += __shfl_xor(vp[j], d);
          }
        }
        if (c == 0) {
          #pragma unroll
          for (int j = 0; j < 4; ++j) {
            s_u[(g * 4 + j) * 64 + l] = up[j];
            s_v[(g * 4 + j) * 64 + l] = vp[j];
          }
        }
      }
    }
    __syncthreads();

    // ==== phase 4: Heun update (owner registers) ====
    {
      const float2 f1v = *(const float2*)&s_f1[r_own * 64 + o_own];
      const float2 u1v = *(const float2*)&s_u[r_own * 64 + o_own];
      const float2 v1v = *(const float2*)&s_v[r_own * 64 + o_own];
      const float dti = (k > 0) ? (tval - s_ts[k - 1]) : 0.f;
      const float dtn = (k < TT - 1) ? (s_ts[k + 1] - tval) : 0.f;
      yA += 0.5f * (fA + f1v.x) * dti + 0.5f * (vA + u1v.x);
      yB += 0.5f * (fB + f1v.y) * dti + 0.5f * (vB + u1v.y);
      zA = 2.f * yA - zA + f1v.x * dtn + v1v.x;
      zB = 2.f * yB - zB + f1v.y * dtn + v1v.y;
      fA = f1v.x; fB = f1v.y; vA = v1v.x; vB = v1v.y;
      float2 zw; zw.x = zA; zw.y = zB;
      *(float2*)&s_z[r_own * 68 + o_own] = zw;
      float2 yw; yw.x = yA; yw.y = yB;
      *(float2*)&s_yb[(k & 3) * 1088 + r_own * 68 + o_own] = yw;
    }
    __syncthreads();

    // ==== batched readout every 4 steps: 64 tokens ====
    if ((k & 3) == 3) {
      {
        const int st = w >> 1;                     // yb step tile
        bf16x8 ahi[2], alo[2];
        build_a<2>(s_yb + st * 1088, 68, c, g, ahi, alo);
        #pragma unroll
        for (int jn = 0; jn < 4; ++jn) {
          const int col = ((w & 1) * 4 + jn) * 16 + c;
          const float ci = s_rb1[col];
          f32x4 acc = {ci, ci, ci, ci};
          #pragma unroll
          for (int kt = 0; kt < 2; ++kt) {
            const bf16x8 b = *(const bf16x8*)(wsu + F_RO1 +
                                              ((size_t)((kt * 4 + g) * 128 + col)) * 8);
            acc = mfma2(ahi[kt], alo[kt], b, acc);
          }
          #pragma unroll
          for (int j = 0; j < 4; ++j)
            s_hro[(st * 16 + g * 4 + j) * 132 + col] = lipswish(acc[j]);
        }
      }
      __syncthreads();
      {
        const int mt = w >> 1, col = (w & 1) * 16 + c;
        bf16x8 ahi[4], alo[4];
        build_a<4>(s_hro + mt * 2112, 132, c, g, ahi, alo);
        const float ci = s_rb2[col];
        f32x4 acc = {ci, ci, ci, ci};
        #pragma unroll
        for (int kt = 0; kt < 4; ++kt) {
          const bf16x8 b = *(const bf16x8*)(wsu + F_RO2 +
                                            ((size_t)((kt * 4 + g) * 32 + col)) * 8);
          acc = mfma2(ahi[kt], alo[kt], b, acc);
        }
        const int tg = k - 3 + mt;
        #pragma unroll
        for (int j = 0; j < 4; ++j) {
          const int r = g * 4 + j;
          out[((size_t)(b0 + r) * TT + tg) * OUTD + col] = acc[j];
          if (mult > 0 && (tg % mult) == 0) {
            const int jj = tg / mult;
            if (jj < steps)
              out[(size_t)NBATCH * TT * OUTD + ((size_t)(b0 + r) * steps + jj) * OUTD + col] = acc[j];
          }
        }
      }
      __syncthreads();
    }
  }
}

extern "C" void kernel_launch(void* const* d_in, const int* in_sizes, int n_in,
                              void* d_out, int out_size, void* d_ws, size_t ws_size,
                              hipStream_t stream) {
  (void)in_sizes; (void)n_in; (void)out_size; (void)ws_size;
  const float* init_noise = (const float*)d_in[0];
  const float* bm_noise   = (const float*)d_in[1];
  const float* ts         = (const float*)d_in[2];
  const int*   p_steps    = (const int*)d_in[3];
  const int*   p_mult     = (const int*)d_in[4];
  const float* emb_W = (const float*)d_in[5];
  const float* emb_b = (const float*)d_in[6];
  const float* dr_v1 = (const float*)d_in[7];
  const float* dr_g1 = (const float*)d_in[8];
  const float* dr_b1 = (const float*)d_in[9];
  const float* dr_v2 = (const float*)d_in[10];
  const float* dr_g2 = (const float*)d_in[11];
  const float* dr_b2 = (const float*)d_in[12];
  const float* dr_v3 = (const float*)d_in[13];
  const float* dr_g3 = (const float*)d_in[14];
  const float* dr_b3 = (const float*)d_in[15];
  const float* di_v1 = (const float*)d_in[16];
  const float* di_g1 = (const float*)d_in[17];
  const float* di_b1 = (const float*)d_in[18];
  const float* di_v2 = (const float*)d_in[19];
  const float* di_g2 = (const float*)d_in[20];
  const float* di_b2 = (const float*)d_in[21];
  const float* di_v3 = (const float*)d_in[22];
  const float* di_g3 = (const float*)d_in[23];
  const float* di_b3 = (const float*)d_in[24];
  const float* ro_W1 = (const float*)d_in[25];
  const float* ro_b1 = (const float*)d_in[26];
  const float* ro_W2 = (const float*)d_in[27];
  const float* ro_b2 = (const float*)d_in[28];
  float* ws = (float*)d_ws;
  float* out = (float*)d_out;

  (void)hipFuncSetAttribute((const void*)sde_main,
                            hipFuncAttributeMaxDynamicSharedMemorySize, 160 * 1024);

  prep_kernel<<<dim3(1024, 9), 128, 0, stream>>>(
      dr_v1, dr_g1, dr_v2, dr_g2, dr_v3, dr_g3,
      di_v1, di_g1, di_v2, di_g2, di_v3, di_g3,
      emb_W, ro_W1, ro_W2, ws);

  sde_main<<<NBLK, 512, 78592, stream>>>(
      init_noise, bm_noise, ts, p_steps, p_mult,
      emb_b, dr_b1, dr_b2, dr_b3, di_b1, di_b2, di_b3,
      ro_b1, ro_b2, ws, out);
}